// Round 1
// baseline (1200.722 us; speedup 1.0000x reference)
//
#include <hip/hip_runtime.h>

#define N_NODES 65536
#define N_EDGES 1048576
// IN_CH=300, HID=64, OUT_CH=20

// ---------------------------------------------------------------------------
// JAX threefry2x32, partitionable path (jax >= 0.4.36 default):
// bits[i] = x0 ^ x1 of threefry2x32(key=(0,42), counter=(hi32(i), lo32(i)))
// keep = bits < 2^31  (uniform(bits) < 0.5)
// ---------------------------------------------------------------------------
__device__ __forceinline__ bool keep_mask(unsigned idx) {
  const unsigned k0 = 0u, k1 = 42u;
  const unsigned k2 = 0x1BD11BDAu ^ k0 ^ k1;
  unsigned x0 = 0u;       // hi word of 64-bit counter (idx < 2^32)
  unsigned x1 = idx;      // lo word
  x0 += k0; x1 += k1;
#define TF_ROUND(r) { x0 += x1; x1 = (x1 << (r)) | (x1 >> (32 - (r))); x1 ^= x0; }
  TF_ROUND(13) TF_ROUND(15) TF_ROUND(26) TF_ROUND(6)
  x0 += k1; x1 += k2 + 1u;
  TF_ROUND(17) TF_ROUND(29) TF_ROUND(16) TF_ROUND(24)
  x0 += k2; x1 += k0 + 2u;
  TF_ROUND(13) TF_ROUND(15) TF_ROUND(26) TF_ROUND(6)
  x0 += k0; x1 += k1 + 3u;
  TF_ROUND(17) TF_ROUND(29) TF_ROUND(16) TF_ROUND(24)
  x0 += k1; x1 += k2 + 4u;
  TF_ROUND(13) TF_ROUND(15) TF_ROUND(26) TF_ROUND(6)
  x0 += k2; x1 += k0 + 5u;
#undef TF_ROUND
  return ((x0 ^ x1) & 0x80000000u) == 0u;
}

// ---------------------------------------------------------------------------
// init: agg1[n][c] = b1[c]  (bias folded into accumulator); out[n][c] = b2[c]
// ---------------------------------------------------------------------------
__global__ void init_bufs(const float* __restrict__ b1, const float* __restrict__ b2,
                          float* __restrict__ agg1, float* __restrict__ out) {
  int gid = blockIdx.x * blockDim.x + threadIdx.x;
  if (gid < N_NODES * 64) agg1[gid] = b1[gid & 63];
  if (gid < N_NODES * 20) out[gid] = b2[gid % 20];
}

// ---------------------------------------------------------------------------
// gemm1: h1 = x @ W1   x:[N,300] W1:[300,64]  block: 64 nodes x 64 ch, K-tile 100
// ---------------------------------------------------------------------------
__global__ __launch_bounds__(256) void gemm1(const float* __restrict__ x,
                                             const float* __restrict__ W1,
                                             float* __restrict__ h1) {
  __shared__ float xs[100][64];   // [k][node]
  __shared__ float ws[100][64];   // [k][ch]
  const int tid = threadIdx.x;
  const int node0 = blockIdx.x * 64;
  const int tx = tid & 15;        // ch group: ch 4*tx .. 4*tx+3
  const int ty = tid >> 4;        // node group: nodes 4*ty .. 4*ty+3
  float acc[4][4] = {};
  for (int kt = 0; kt < 3; ++kt) {
    const int k0 = kt * 100;
    // stage x tile: 64 nodes x 100 k = 1600 float4; lane->node (conflict-free LDS)
    for (int f = tid; f < 1600; f += 256) {
      int node = f & 63;
      int kq = f >> 6;            // 0..24
      float4 v = *(const float4*)(x + (size_t)(node0 + node) * 300 + k0 + kq * 4);
      xs[kq * 4 + 0][node] = v.x;
      xs[kq * 4 + 1][node] = v.y;
      xs[kq * 4 + 2][node] = v.z;
      xs[kq * 4 + 3][node] = v.w;
    }
    // stage W tile: 100 k x 64 ch = 1600 float4, coalesced
    for (int f = tid; f < 1600; f += 256) {
      int k = f >> 4;
      int cq = f & 15;
      *(float4*)(&ws[k][cq * 4]) = *(const float4*)(W1 + (size_t)(k0 + k) * 64 + cq * 4);
    }
    __syncthreads();
#pragma unroll 4
    for (int k = 0; k < 100; ++k) {
      float4 wv = *(const float4*)(&ws[k][tx * 4]);
      float4 xv = *(const float4*)(&xs[k][ty * 4]);
      acc[0][0] = fmaf(xv.x, wv.x, acc[0][0]); acc[0][1] = fmaf(xv.x, wv.y, acc[0][1]);
      acc[0][2] = fmaf(xv.x, wv.z, acc[0][2]); acc[0][3] = fmaf(xv.x, wv.w, acc[0][3]);
      acc[1][0] = fmaf(xv.y, wv.x, acc[1][0]); acc[1][1] = fmaf(xv.y, wv.y, acc[1][1]);
      acc[1][2] = fmaf(xv.y, wv.z, acc[1][2]); acc[1][3] = fmaf(xv.y, wv.w, acc[1][3]);
      acc[2][0] = fmaf(xv.z, wv.x, acc[2][0]); acc[2][1] = fmaf(xv.z, wv.y, acc[2][1]);
      acc[2][2] = fmaf(xv.z, wv.z, acc[2][2]); acc[2][3] = fmaf(xv.z, wv.w, acc[2][3]);
      acc[3][0] = fmaf(xv.w, wv.x, acc[3][0]); acc[3][1] = fmaf(xv.w, wv.y, acc[3][1]);
      acc[3][2] = fmaf(xv.w, wv.z, acc[3][2]); acc[3][3] = fmaf(xv.w, wv.w, acc[3][3]);
    }
    __syncthreads();
  }
#pragma unroll
  for (int ni = 0; ni < 4; ++ni) {
    float4 o = make_float4(acc[ni][0], acc[ni][1], acc[ni][2], acc[ni][3]);
    *(float4*)(h1 + (size_t)(node0 + ty * 4 + ni) * 64 + tx * 4) = o;
  }
}

// ---------------------------------------------------------------------------
// scatter1: agg1[dst] += w * h1[src]   16 threads/edge x float4 (64 ch)
// ---------------------------------------------------------------------------
__global__ __launch_bounds__(256) void scatter1(const int* __restrict__ ei,
                                                const float* __restrict__ ew,
                                                const float* __restrict__ h1,
                                                float* __restrict__ agg) {
  int gid = blockIdx.x * blockDim.x + threadIdx.x;
  int e = gid >> 4, cg = gid & 15;
  if (e >= N_EDGES) return;
  int src = ei[e];
  int dst = ei[N_EDGES + e];
  float w = ew[e];
  float4 v = *(const float4*)(h1 + (size_t)src * 64 + cg * 4);
  float* p = agg + (size_t)dst * 64 + cg * 4;
  atomicAdd(p + 0, w * v.x);
  atomicAdd(p + 1, w * v.y);
  atomicAdd(p + 2, w * v.z);
  atomicAdd(p + 3, w * v.w);
}

// ---------------------------------------------------------------------------
// gemm2: h2 = relu(agg1) * mask * 2 ;  g = h2 @ W2   (W2: [64][20])
// block = 320 threads = 16 nodes x 20 ch
// ---------------------------------------------------------------------------
__global__ __launch_bounds__(320) void gemm2(const float* __restrict__ agg1,
                                             const float* __restrict__ W2,
                                             float* __restrict__ g) {
  __shared__ float hs[16][64];
  __shared__ float wst[20][68];   // transposed W2, +4 pad for bank spread
  const int tid = threadIdx.x;
  const int node0 = blockIdx.x * 16;
  for (int i = tid; i < 16 * 64; i += 320) {
    int n = i >> 6, c = i & 63;
    unsigned gi = (unsigned)(node0 + n) * 64u + (unsigned)c;
    float v = agg1[gi];
    v = fmaxf(v, 0.0f);
    v = keep_mask(gi) ? v * 2.0f : 0.0f;
    hs[n][c] = v;
  }
  for (int i = tid; i < 64 * 20; i += 320) {
    wst[i % 20][i / 20] = W2[i];
  }
  __syncthreads();
  const int n = tid / 20, c = tid % 20;
  float acc = 0.0f;
#pragma unroll
  for (int k = 0; k < 64; k += 4) {
    float4 hv = *(const float4*)(&hs[n][k]);
    float4 wv = *(const float4*)(&wst[c][k]);
    acc = fmaf(hv.x, wv.x, acc);
    acc = fmaf(hv.y, wv.y, acc);
    acc = fmaf(hv.z, wv.z, acc);
    acc = fmaf(hv.w, wv.w, acc);
  }
  g[(size_t)(node0 + n) * 20 + c] = acc;
}

// ---------------------------------------------------------------------------
// scatter2: out[dst] += w * g[src]   (20 ch, 1 thread per (edge, ch))
// ---------------------------------------------------------------------------
__global__ __launch_bounds__(256) void scatter2(const int* __restrict__ ei,
                                                const float* __restrict__ ew,
                                                const float* __restrict__ g,
                                                float* __restrict__ out) {
  long long gid = (long long)blockIdx.x * blockDim.x + threadIdx.x;
  int e = (int)(gid / 20);
  int c = (int)(gid % 20);
  if (e >= N_EDGES) return;
  int src = ei[e];
  int dst = ei[N_EDGES + e];
  float w = ew[e];
  atomicAdd(out + (size_t)dst * 20 + c, w * g[(size_t)src * 20 + c]);
}

extern "C" void kernel_launch(void* const* d_in, const int* in_sizes, int n_in,
                              void* d_out, int out_size, void* d_ws, size_t ws_size,
                              hipStream_t stream) {
  const float* x  = (const float*)d_in[0];
  const int*   ei = (const int*)d_in[1];   // int32 per harness contract
  const float* ew = (const float*)d_in[2];
  const float* W1 = (const float*)d_in[3];
  const float* b1 = (const float*)d_in[4];
  const float* W2 = (const float*)d_in[5];
  const float* b2 = (const float*)d_in[6];
  float* out = (float*)d_out;

  float* h1   = (float*)d_ws;                 // N*64 floats
  float* agg1 = h1 + (size_t)N_NODES * 64;    // N*64 floats
  float* g    = h1;                           // alias: h1 dead after scatter1

  init_bufs<<<(N_NODES * 64 + 255) / 256, 256, 0, stream>>>(b1, b2, agg1, out);
  gemm1<<<N_NODES / 64, 256, 0, stream>>>(x, W1, h1);
  scatter1<<<(N_EDGES * 16) / 256, 256, 0, stream>>>(ei, ew, h1, agg1);
  gemm2<<<N_NODES / 16, 320, 0, stream>>>(agg1, W2, g);
  scatter2<<<(N_EDGES * 20 + 255) / 256, 256, 0, stream>>>(ei, ew, g, out);
}

// Round 2
// 435.222 us; speedup vs baseline: 2.7589x; 2.7589x over previous
//
#include <hip/hip_runtime.h>

#define N_NODES 65536
#define N_EDGES 1048576
// IN_CH=300, HID=64, OUT_CH=20

// ---------------------------------------------------------------------------
// JAX threefry2x32, partitionable path: bits[i] = x0^x1 of
// threefry2x32(key=(0,42), counter=(0,i)); keep = MSB==0.  [verified R1]
// ---------------------------------------------------------------------------
__device__ __forceinline__ bool keep_mask(unsigned idx) {
  const unsigned k0 = 0u, k1 = 42u;
  const unsigned k2 = 0x1BD11BDAu ^ k0 ^ k1;
  unsigned x0 = 0u;
  unsigned x1 = idx;
  x0 += k0; x1 += k1;
#define TF_ROUND(r) { x0 += x1; x1 = (x1 << (r)) | (x1 >> (32 - (r))); x1 ^= x0; }
  TF_ROUND(13) TF_ROUND(15) TF_ROUND(26) TF_ROUND(6)
  x0 += k1; x1 += k2 + 1u;
  TF_ROUND(17) TF_ROUND(29) TF_ROUND(16) TF_ROUND(24)
  x0 += k2; x1 += k0 + 2u;
  TF_ROUND(13) TF_ROUND(15) TF_ROUND(26) TF_ROUND(6)
  x0 += k0; x1 += k1 + 3u;
  TF_ROUND(17) TF_ROUND(29) TF_ROUND(16) TF_ROUND(24)
  x0 += k1; x1 += k2 + 4u;
  TF_ROUND(13) TF_ROUND(15) TF_ROUND(26) TF_ROUND(6)
  x0 += k2; x1 += k0 + 5u;
#undef TF_ROUND
  return ((x0 ^ x1) & 0x80000000u) == 0u;
}

// ===========================================================================
// CSR build (counting sort of edges by dst)
// ===========================================================================
__global__ void zero_u32(unsigned* __restrict__ p, int n) {
  int i = blockIdx.x * blockDim.x + threadIdx.x;
  if (i < n) p[i] = 0u;
}

__global__ void hist_dst(const int* __restrict__ ei, unsigned* __restrict__ deg) {
  int e = blockIdx.x * blockDim.x + threadIdx.x;
  if (e < N_EDGES) atomicAdd(&deg[ei[N_EDGES + e]], 1u);
}

// single-block exclusive scan of 65536 degrees (in-place -> start offsets),
// plus a cursor copy in pos[].
__global__ __launch_bounds__(1024) void scan_deg(unsigned* __restrict__ offs,
                                                 unsigned* __restrict__ pos) {
  __shared__ unsigned ls[1024];
  const int t = threadIdx.x;
  unsigned s = 0;
  for (int j = 0; j < 64; ++j) s += offs[t * 64 + j];
  ls[t] = s;
  __syncthreads();
  for (int d = 1; d < 1024; d <<= 1) {
    unsigned v = (t >= d) ? ls[t - d] : 0u;
    __syncthreads();
    ls[t] += v;
    __syncthreads();
  }
  unsigned run = ls[t] - s;  // exclusive prefix of this thread's chunk
  for (int j = 0; j < 64; ++j) {
    int idx = t * 64 + j;
    unsigned v = offs[idx];
    offs[idx] = run;
    pos[idx] = run;
    run += v;
  }
}

// place (src, weight) into dst-sorted order; after this, pos[n] == end(n)
__global__ void reorder(const int* __restrict__ ei, const float* __restrict__ ew,
                        unsigned* __restrict__ pos, uint2* __restrict__ sorted) {
  int e = blockIdx.x * blockDim.x + threadIdx.x;
  if (e >= N_EDGES) return;
  int d = ei[N_EDGES + e];
  unsigned p = atomicAdd(&pos[d], 1u);
  uint2 sw;
  sw.x = (unsigned)ei[e];
  sw.y = __float_as_uint(ew[e]);
  sorted[p] = sw;
}

// ===========================================================================
// gemm1: h1 = x @ W1   x:[N,300] W1:[300,64]  block: 64 nodes x 64 ch
// ===========================================================================
__global__ __launch_bounds__(256) void gemm1(const float* __restrict__ x,
                                             const float* __restrict__ W1,
                                             float* __restrict__ h1) {
  __shared__ float xs[100][64];
  __shared__ float ws[100][64];
  const int tid = threadIdx.x;
  const int node0 = blockIdx.x * 64;
  const int tx = tid & 15;
  const int ty = tid >> 4;
  float acc[4][4] = {};
  for (int kt = 0; kt < 3; ++kt) {
    const int k0 = kt * 100;
    for (int f = tid; f < 1600; f += 256) {
      int node = f & 63;
      int kq = f >> 6;
      float4 v = *(const float4*)(x + (size_t)(node0 + node) * 300 + k0 + kq * 4);
      xs[kq * 4 + 0][node] = v.x;
      xs[kq * 4 + 1][node] = v.y;
      xs[kq * 4 + 2][node] = v.z;
      xs[kq * 4 + 3][node] = v.w;
    }
    for (int f = tid; f < 1600; f += 256) {
      int k = f >> 4;
      int cq = f & 15;
      *(float4*)(&ws[k][cq * 4]) = *(const float4*)(W1 + (size_t)(k0 + k) * 64 + cq * 4);
    }
    __syncthreads();
#pragma unroll 4
    for (int k = 0; k < 100; ++k) {
      float4 wv = *(const float4*)(&ws[k][tx * 4]);
      float4 xv = *(const float4*)(&xs[k][ty * 4]);
      acc[0][0] = fmaf(xv.x, wv.x, acc[0][0]); acc[0][1] = fmaf(xv.x, wv.y, acc[0][1]);
      acc[0][2] = fmaf(xv.x, wv.z, acc[0][2]); acc[0][3] = fmaf(xv.x, wv.w, acc[0][3]);
      acc[1][0] = fmaf(xv.y, wv.x, acc[1][0]); acc[1][1] = fmaf(xv.y, wv.y, acc[1][1]);
      acc[1][2] = fmaf(xv.y, wv.z, acc[1][2]); acc[1][3] = fmaf(xv.y, wv.w, acc[1][3]);
      acc[2][0] = fmaf(xv.z, wv.x, acc[2][0]); acc[2][1] = fmaf(xv.z, wv.y, acc[2][1]);
      acc[2][2] = fmaf(xv.z, wv.z, acc[2][2]); acc[2][3] = fmaf(xv.z, wv.w, acc[2][3]);
      acc[3][0] = fmaf(xv.w, wv.x, acc[3][0]); acc[3][1] = fmaf(xv.w, wv.y, acc[3][1]);
      acc[3][2] = fmaf(xv.w, wv.z, acc[3][2]); acc[3][3] = fmaf(xv.w, wv.w, acc[3][3]);
    }
    __syncthreads();
  }
#pragma unroll
  for (int ni = 0; ni < 4; ++ni) {
    float4 o = make_float4(acc[ni][0], acc[ni][1], acc[ni][2], acc[ni][3]);
    *(float4*)(h1 + (size_t)(node0 + ty * 4 + ni) * 64 + tx * 4) = o;
  }
}

// ===========================================================================
// aggregate1: agg1[n][:] = b1 + sum_{e in CSR(n)} w_e * h1[src_e][:]
// 16 lanes per node (float4 each), no atomics, coalesced store
// ===========================================================================
__global__ __launch_bounds__(256) void aggregate1(const unsigned* __restrict__ offs,
                                                  const unsigned* __restrict__ pos,
                                                  const uint2* __restrict__ sorted,
                                                  const float* __restrict__ h1,
                                                  const float* __restrict__ b1,
                                                  float* __restrict__ agg1) {
  const int tid = threadIdx.x;
  const int n = blockIdx.x * 16 + (tid >> 4);
  const int cg = tid & 15;
  const unsigned s = offs[n], e_end = pos[n];
  float4 acc = *(const float4*)(b1 + cg * 4);
  for (unsigned e = s; e < e_end; ++e) {
    uint2 sw = sorted[e];
    float w = __uint_as_float(sw.y);
    float4 v = *(const float4*)(h1 + (size_t)sw.x * 64 + cg * 4);
    acc.x = fmaf(w, v.x, acc.x);
    acc.y = fmaf(w, v.y, acc.y);
    acc.z = fmaf(w, v.z, acc.z);
    acc.w = fmaf(w, v.w, acc.w);
  }
  *(float4*)(agg1 + (size_t)n * 64 + cg * 4) = acc;
}

// ===========================================================================
// gemm2: h2 = relu(agg1)*mask*2 ; g = h2 @ W2  (block = 16 nodes x 20 ch)
// ===========================================================================
__global__ __launch_bounds__(320) void gemm2(const float* __restrict__ agg1,
                                             const float* __restrict__ W2,
                                             float* __restrict__ g) {
  __shared__ float hs[16][64];
  __shared__ float wst[20][68];
  const int tid = threadIdx.x;
  const int node0 = blockIdx.x * 16;
  for (int i = tid; i < 16 * 64; i += 320) {
    int n = i >> 6, c = i & 63;
    unsigned gi = (unsigned)(node0 + n) * 64u + (unsigned)c;
    float v = agg1[gi];
    v = fmaxf(v, 0.0f);
    v = keep_mask(gi) ? v * 2.0f : 0.0f;
    hs[n][c] = v;
  }
  for (int i = tid; i < 64 * 20; i += 320) {
    wst[i % 20][i / 20] = W2[i];
  }
  __syncthreads();
  const int n = tid / 20, c = tid % 20;
  float acc = 0.0f;
#pragma unroll
  for (int k = 0; k < 64; k += 4) {
    float4 hv = *(const float4*)(&hs[n][k]);
    float4 wv = *(const float4*)(&wst[c][k]);
    acc = fmaf(hv.x, wv.x, acc);
    acc = fmaf(hv.y, wv.y, acc);
    acc = fmaf(hv.z, wv.z, acc);
    acc = fmaf(hv.w, wv.w, acc);
  }
  g[(size_t)(node0 + n) * 20 + c] = acc;
}

// ===========================================================================
// aggregate2: out[n][c] = b2[c] + sum_{e in CSR(n)} w_e * g[src_e][c]
// 20 lanes per node, no atomics, coalesced store
// ===========================================================================
__global__ __launch_bounds__(320) void aggregate2(const unsigned* __restrict__ offs,
                                                  const unsigned* __restrict__ pos,
                                                  const uint2* __restrict__ sorted,
                                                  const float* __restrict__ g,
                                                  const float* __restrict__ b2,
                                                  float* __restrict__ out) {
  const int tid = threadIdx.x;
  const int n = blockIdx.x * 16 + tid / 20;
  const int c = tid % 20;
  const unsigned s = offs[n], e_end = pos[n];
  float acc = b2[c];
  for (unsigned e = s; e < e_end; ++e) {
    uint2 sw = sorted[e];
    acc = fmaf(__uint_as_float(sw.y), g[(size_t)sw.x * 20 + c], acc);
  }
  out[(size_t)n * 20 + c] = acc;
}

// ===========================================================================
// Fallback (R1 atomic path) — used only if ws_size too small for CSR
// ===========================================================================
__global__ void init_bufs(const float* __restrict__ b1, const float* __restrict__ b2,
                          float* __restrict__ agg1, float* __restrict__ out) {
  int gid = blockIdx.x * blockDim.x + threadIdx.x;
  if (gid < N_NODES * 64) agg1[gid] = b1[gid & 63];
  if (gid < N_NODES * 20) out[gid] = b2[gid % 20];
}

__global__ __launch_bounds__(256) void scatter1(const int* __restrict__ ei,
                                                const float* __restrict__ ew,
                                                const float* __restrict__ h1,
                                                float* __restrict__ agg) {
  int gid = blockIdx.x * blockDim.x + threadIdx.x;
  int e = gid >> 4, cg = gid & 15;
  if (e >= N_EDGES) return;
  int src = ei[e];
  int dst = ei[N_EDGES + e];
  float w = ew[e];
  float4 v = *(const float4*)(h1 + (size_t)src * 64 + cg * 4);
  float* p = agg + (size_t)dst * 64 + cg * 4;
  atomicAdd(p + 0, w * v.x);
  atomicAdd(p + 1, w * v.y);
  atomicAdd(p + 2, w * v.z);
  atomicAdd(p + 3, w * v.w);
}

__global__ __launch_bounds__(256) void scatter2(const int* __restrict__ ei,
                                                const float* __restrict__ ew,
                                                const float* __restrict__ g,
                                                float* __restrict__ out) {
  long long gid = (long long)blockIdx.x * blockDim.x + threadIdx.x;
  int e = (int)(gid / 20);
  int c = (int)(gid % 20);
  if (e >= N_EDGES) return;
  int src = ei[e];
  int dst = ei[N_EDGES + e];
  float w = ew[e];
  atomicAdd(out + (size_t)dst * 20 + c, w * g[(size_t)src * 20 + c]);
}

extern "C" void kernel_launch(void* const* d_in, const int* in_sizes, int n_in,
                              void* d_out, int out_size, void* d_ws, size_t ws_size,
                              hipStream_t stream) {
  const float* x  = (const float*)d_in[0];
  const int*   ei = (const int*)d_in[1];
  const float* ew = (const float*)d_in[2];
  const float* W1 = (const float*)d_in[3];
  const float* b1 = (const float*)d_in[4];
  const float* W2 = (const float*)d_in[5];
  const float* b2 = (const float*)d_in[6];
  float* out = (float*)d_out;

  const size_t H = (size_t)N_NODES * 64;       // 4,194,304 floats
  float* h1   = (float*)d_ws;                  // [H] floats; aliased as g later
  float* agg1 = h1 + H;                        // [H] floats
  float* g    = h1;                            // h1 dead after aggregate1

  const size_t csr_need = (2 * H + 2 * (size_t)N_NODES) * 4 + (size_t)N_EDGES * 8;

  if (ws_size >= csr_need) {
    unsigned* offs = (unsigned*)(agg1 + H);            // [N]
    unsigned* pos  = offs + N_NODES;                   // [N]
    uint2*   sorted = (uint2*)(pos + N_NODES);         // [E], 8B-aligned

    zero_u32<<<N_NODES / 256, 256, 0, stream>>>(offs, N_NODES);
    hist_dst<<<N_EDGES / 256, 256, 0, stream>>>(ei, offs);
    scan_deg<<<1, 1024, 0, stream>>>(offs, pos);
    reorder<<<N_EDGES / 256, 256, 0, stream>>>(ei, ew, pos, sorted);

    gemm1<<<N_NODES / 64, 256, 0, stream>>>(x, W1, h1);
    aggregate1<<<N_NODES / 16, 256, 0, stream>>>(offs, pos, sorted, h1, b1, agg1);
    gemm2<<<N_NODES / 16, 320, 0, stream>>>(agg1, W2, g);
    aggregate2<<<N_NODES / 16, 320, 0, stream>>>(offs, pos, sorted, g, b2, out);
  } else {
    init_bufs<<<(N_NODES * 64 + 255) / 256, 256, 0, stream>>>(b1, b2, agg1, out);
    gemm1<<<N_NODES / 64, 256, 0, stream>>>(x, W1, h1);
    scatter1<<<(N_EDGES * 16) / 256, 256, 0, stream>>>(ei, ew, h1, agg1);
    gemm2<<<N_NODES / 16, 320, 0, stream>>>(agg1, W2, g);
    scatter2<<<(N_EDGES * 20 + 255) / 256, 256, 0, stream>>>(ei, ew, g, out);
  }
}

// Round 3
// 320.341 us; speedup vs baseline: 3.7483x; 1.3586x over previous
//
#include <hip/hip_runtime.h>

#define N_NODES 65536
#define N_EDGES 1048576
#define NB 256            // coarse buckets = dst >> 8
#define EPB_A 2048        // edges per block in bin_pass
#define BLK_A (N_EDGES / EPB_A)   // 512
#define EPT_A (EPB_A / 256)       // 8 edges per thread

// ---------------------------------------------------------------------------
// JAX threefry2x32, partitionable path: bits[i] = x0^x1 of
// threefry2x32(key=(0,42), counter=(0,i)); keep = MSB==0.  [verified R1]
// ---------------------------------------------------------------------------
__device__ __forceinline__ bool keep_mask(unsigned idx) {
  const unsigned k0 = 0u, k1 = 42u;
  const unsigned k2 = 0x1BD11BDAu ^ k0 ^ k1;
  unsigned x0 = 0u;
  unsigned x1 = idx;
  x0 += k0; x1 += k1;
#define TF_ROUND(r) { x0 += x1; x1 = (x1 << (r)) | (x1 >> (32 - (r))); x1 ^= x0; }
  TF_ROUND(13) TF_ROUND(15) TF_ROUND(26) TF_ROUND(6)
  x0 += k1; x1 += k2 + 1u;
  TF_ROUND(17) TF_ROUND(29) TF_ROUND(16) TF_ROUND(24)
  x0 += k2; x1 += k0 + 2u;
  TF_ROUND(13) TF_ROUND(15) TF_ROUND(26) TF_ROUND(6)
  x0 += k0; x1 += k1 + 3u;
  TF_ROUND(17) TF_ROUND(29) TF_ROUND(16) TF_ROUND(24)
  x0 += k1; x1 += k2 + 4u;
  TF_ROUND(13) TF_ROUND(15) TF_ROUND(26) TF_ROUND(6)
  x0 += k2; x1 += k0 + 5u;
#undef TF_ROUND
  return ((x0 ^ x1) & 0x80000000u) == 0u;
}

// ===========================================================================
// Sort stage 1: coarse-bucket histogram (LDS-privatized)
// ===========================================================================
__global__ __launch_bounds__(256) void hist_buckets(const int* __restrict__ ei,
                                                    unsigned* __restrict__ bcnt) {
  __shared__ unsigned cnt[NB];
  const int t = threadIdx.x;
  cnt[t] = 0u;
  __syncthreads();
  const int e0 = blockIdx.x * 4096;
#pragma unroll
  for (int j = 0; j < 16; ++j) {
    int d = ei[N_EDGES + e0 + t + j * 256];
    atomicAdd(&cnt[d >> 8], 1u);
  }
  __syncthreads();
  atomicAdd(&bcnt[t], cnt[t]);
}

// ===========================================================================
// Sort stage 2: scan 256 bucket counts -> bucket offsets + grab cursors
// ===========================================================================
__global__ __launch_bounds__(256) void scan_buckets(const unsigned* __restrict__ bcnt,
                                                    unsigned* __restrict__ boffs,
                                                    unsigned* __restrict__ gcur) {
  __shared__ unsigned ls[NB];
  const int t = threadIdx.x;
  unsigned v = bcnt[t];
  ls[t] = v;
  __syncthreads();
  for (int d = 1; d < NB; d <<= 1) {
    unsigned u = (t >= d) ? ls[t - d] : 0u;
    __syncthreads();
    ls[t] += u;
    __syncthreads();
  }
  unsigned excl = ls[t] - v;
  boffs[t] = excl;
  gcur[t] = excl;
  if (t == NB - 1) boffs[NB] = ls[t];
}

// ===========================================================================
// Sort stage 3: multisplit — LDS-stage edges by bucket, write contiguous runs
// pack: x = src | (dst << 16)   (both < 65536), y = weight bits
// ===========================================================================
__global__ __launch_bounds__(256) void bin_pass(const int* __restrict__ ei,
                                                const float* __restrict__ ew,
                                                unsigned* __restrict__ gcur,
                                                uint2* __restrict__ binned) {
  __shared__ unsigned cnt[NB], lofs[NB], lcur[NB], gbase[NB];
  __shared__ uint2 stage[EPB_A];
  const int t = threadIdx.x;
  const int e0 = blockIdx.x * EPB_A;
  cnt[t] = 0u;
  lcur[t] = 0u;
  __syncthreads();
  unsigned pk[EPT_A], pw[EPT_A];
#pragma unroll
  for (int j = 0; j < EPT_A; ++j) {
    int e = e0 + t + j * 256;
    unsigned s = (unsigned)ei[e];
    unsigned d = (unsigned)ei[N_EDGES + e];
    pk[j] = s | (d << 16);
    pw[j] = __float_as_uint(ew[e]);
    atomicAdd(&cnt[d >> 8], 1u);
  }
  __syncthreads();
  // exclusive scan of cnt into lofs
  lofs[t] = cnt[t];
  __syncthreads();
  for (int d = 1; d < NB; d <<= 1) {
    unsigned u = (t >= d) ? lofs[t - d] : 0u;
    __syncthreads();
    lofs[t] += u;
    __syncthreads();
  }
  unsigned incl = lofs[t];
  lofs[t] = incl - cnt[t];
  gbase[t] = atomicAdd(&gcur[t], cnt[t]);
  __syncthreads();
#pragma unroll
  for (int j = 0; j < EPT_A; ++j) {
    unsigned b = pk[j] >> 24;
    unsigned slot = lofs[b] + atomicAdd(&lcur[b], 1u);
    stage[slot] = make_uint2(pk[j], pw[j]);
  }
  __syncthreads();
  for (int s = t; s < EPB_A; s += 256) {
    uint2 u = stage[s];
    unsigned b = u.x >> 24;
    binned[gbase[b] + ((unsigned)s - lofs[b])] = u;
  }
}

// ===========================================================================
// Sort stage 4: per-bucket counting sort by dst low-8; emits CSR offs/ends.
// All stores confined to this bucket's ~32KB region -> L2-absorbed.
// ===========================================================================
__global__ __launch_bounds__(256) void bucket_sort(const unsigned* __restrict__ boffs,
                                                   const uint2* __restrict__ binned,
                                                   uint2* __restrict__ sorted,
                                                   unsigned* __restrict__ offs_g,
                                                   unsigned* __restrict__ ends_g) {
  __shared__ unsigned cnt[NB], cur[NB];
  const int t = threadIdx.x;
  const int b = blockIdx.x;
  const unsigned lo = boffs[b], hi = boffs[b + 1];
  cnt[t] = 0u;
  __syncthreads();
  for (unsigned i = lo + t; i < hi; i += 256) {
    unsigned lo8 = (binned[i].x >> 16) & 255u;
    atomicAdd(&cnt[lo8], 1u);
  }
  __syncthreads();
  cur[t] = cnt[t];
  __syncthreads();
  for (int d = 1; d < NB; d <<= 1) {
    unsigned u = (t >= d) ? cur[t - d] : 0u;
    __syncthreads();
    cur[t] += u;
    __syncthreads();
  }
  unsigned excl = cur[t] - cnt[t];
  unsigned node_start = lo + excl;
  offs_g[b * NB + t] = node_start;
  ends_g[b * NB + t] = node_start + cnt[t];
  __syncthreads();
  cur[t] = excl;
  __syncthreads();
  for (unsigned i = lo + t; i < hi; i += 256) {
    uint2 u = binned[i];
    unsigned lo8 = (u.x >> 16) & 255u;
    unsigned p = lo + atomicAdd(&cur[lo8], 1u);
    sorted[p] = make_uint2(u.x & 0xFFFFu, u.y);
  }
}

// ===========================================================================
// gemm1: h1 = x @ W1   x:[N,300] W1:[300,64]  block: 64 nodes x 64 ch
// ===========================================================================
__global__ __launch_bounds__(256) void gemm1(const float* __restrict__ x,
                                             const float* __restrict__ W1,
                                             float* __restrict__ h1) {
  __shared__ float xs[100][64];
  __shared__ float ws[100][64];
  const int tid = threadIdx.x;
  const int node0 = blockIdx.x * 64;
  const int tx = tid & 15;
  const int ty = tid >> 4;
  float acc[4][4] = {};
  for (int kt = 0; kt < 3; ++kt) {
    const int k0 = kt * 100;
    for (int f = tid; f < 1600; f += 256) {
      int node = f & 63;
      int kq = f >> 6;
      float4 v = *(const float4*)(x + (size_t)(node0 + node) * 300 + k0 + kq * 4);
      xs[kq * 4 + 0][node] = v.x;
      xs[kq * 4 + 1][node] = v.y;
      xs[kq * 4 + 2][node] = v.z;
      xs[kq * 4 + 3][node] = v.w;
    }
    for (int f = tid; f < 1600; f += 256) {
      int k = f >> 4;
      int cq = f & 15;
      *(float4*)(&ws[k][cq * 4]) = *(const float4*)(W1 + (size_t)(k0 + k) * 64 + cq * 4);
    }
    __syncthreads();
#pragma unroll 4
    for (int k = 0; k < 100; ++k) {
      float4 wv = *(const float4*)(&ws[k][tx * 4]);
      float4 xv = *(const float4*)(&xs[k][ty * 4]);
      acc[0][0] = fmaf(xv.x, wv.x, acc[0][0]); acc[0][1] = fmaf(xv.x, wv.y, acc[0][1]);
      acc[0][2] = fmaf(xv.x, wv.z, acc[0][2]); acc[0][3] = fmaf(xv.x, wv.w, acc[0][3]);
      acc[1][0] = fmaf(xv.y, wv.x, acc[1][0]); acc[1][1] = fmaf(xv.y, wv.y, acc[1][1]);
      acc[1][2] = fmaf(xv.y, wv.z, acc[1][2]); acc[1][3] = fmaf(xv.y, wv.w, acc[1][3]);
      acc[2][0] = fmaf(xv.z, wv.x, acc[2][0]); acc[2][1] = fmaf(xv.z, wv.y, acc[2][1]);
      acc[2][2] = fmaf(xv.z, wv.z, acc[2][2]); acc[2][3] = fmaf(xv.z, wv.w, acc[2][3]);
      acc[3][0] = fmaf(xv.w, wv.x, acc[3][0]); acc[3][1] = fmaf(xv.w, wv.y, acc[3][1]);
      acc[3][2] = fmaf(xv.w, wv.z, acc[3][2]); acc[3][3] = fmaf(xv.w, wv.w, acc[3][3]);
    }
    __syncthreads();
  }
#pragma unroll
  for (int ni = 0; ni < 4; ++ni) {
    float4 o = make_float4(acc[ni][0], acc[ni][1], acc[ni][2], acc[ni][3]);
    *(float4*)(h1 + (size_t)(node0 + ty * 4 + ni) * 64 + tx * 4) = o;
  }
}

// ===========================================================================
// Fused: agg1 = b1 + sum_e w*h1[src]; h2 = mask.relu(agg1)*2; g = h2 @ W2
// 256 threads = 16 nodes x 16 lanes (float4); gemm2 tail uses LDS h2.
// ===========================================================================
__global__ __launch_bounds__(256) void agg1_gemm2(const unsigned* __restrict__ offs_g,
                                                  const unsigned* __restrict__ ends_g,
                                                  const uint2* __restrict__ sorted,
                                                  const float* __restrict__ h1,
                                                  const float* __restrict__ b1,
                                                  const float* __restrict__ W2,
                                                  float* __restrict__ g) {
  __shared__ float h2[16][68];    // +4 pad
  __shared__ float w2t[20][68];   // transposed W2
  const int t = threadIdx.x;
  const int node0 = blockIdx.x * 16;
  for (int i = t; i < 64 * 20; i += 256) {
    w2t[i % 20][i / 20] = W2[i];
  }
  const int n = t >> 4, cg = t & 15;
  const int node = node0 + n;
  const unsigned s = offs_g[node], e_end = ends_g[node];
  float4 acc = *(const float4*)(b1 + cg * 4);
  for (unsigned i = s; i < e_end; ++i) {
    uint2 sw = sorted[i];
    float w = __uint_as_float(sw.y);
    float4 v = *(const float4*)(h1 + (size_t)sw.x * 64 + cg * 4);
    acc.x = fmaf(w, v.x, acc.x);
    acc.y = fmaf(w, v.y, acc.y);
    acc.z = fmaf(w, v.z, acc.z);
    acc.w = fmaf(w, v.w, acc.w);
  }
  const unsigned gi = (unsigned)node * 64u + (unsigned)cg * 4u;
  float r[4] = {acc.x, acc.y, acc.z, acc.w};
#pragma unroll
  for (int j = 0; j < 4; ++j) {
    float v = fmaxf(r[j], 0.0f);
    h2[n][cg * 4 + j] = keep_mask(gi + j) ? v * 2.0f : 0.0f;
  }
  __syncthreads();
  for (int o = t; o < 320; o += 256) {
    int n2 = o / 20, c = o % 20;
    float a = 0.0f;
#pragma unroll
    for (int k = 0; k < 64; k += 4) {
      float4 hv = *(const float4*)(&h2[n2][k]);
      float4 wv = *(const float4*)(&w2t[c][k]);
      a = fmaf(hv.x, wv.x, a);
      a = fmaf(hv.y, wv.y, a);
      a = fmaf(hv.z, wv.z, a);
      a = fmaf(hv.w, wv.w, a);
    }
    g[(size_t)(node0 + n2) * 20 + c] = a;
  }
}

// ===========================================================================
// aggregate2: out[n][c] = b2[c] + sum_{e in CSR(n)} w_e * g[src_e][c]
// ===========================================================================
__global__ __launch_bounds__(320) void aggregate2(const unsigned* __restrict__ offs_g,
                                                  const unsigned* __restrict__ ends_g,
                                                  const uint2* __restrict__ sorted,
                                                  const float* __restrict__ g,
                                                  const float* __restrict__ b2,
                                                  float* __restrict__ out) {
  const int tid = threadIdx.x;
  const int n = blockIdx.x * 16 + tid / 20;
  const int c = tid % 20;
  const unsigned s = offs_g[n], e_end = ends_g[n];
  float acc = b2[c];
  for (unsigned e = s; e < e_end; ++e) {
    uint2 sw = sorted[e];
    acc = fmaf(__uint_as_float(sw.y), g[(size_t)sw.x * 20 + c], acc);
  }
  out[(size_t)n * 20 + c] = acc;
}

extern "C" void kernel_launch(void* const* d_in, const int* in_sizes, int n_in,
                              void* d_out, int out_size, void* d_ws, size_t ws_size,
                              hipStream_t stream) {
  const float* x  = (const float*)d_in[0];
  const int*   ei = (const int*)d_in[1];
  const float* ew = (const float*)d_in[2];
  const float* W1 = (const float*)d_in[3];
  const float* b1 = (const float*)d_in[4];
  const float* W2 = (const float*)d_in[5];
  const float* b2 = (const float*)d_in[6];
  float* out = (float*)d_out;

  // workspace layout (needs ~39.3 MB; R2 confirmed ws >= 42.4 MB)
  float*    h1     = (float*)d_ws;                       // N*64 floats, 16MB
  float*    g      = h1 + (size_t)N_NODES * 64;          // N*20 floats, 5MB
  uint2*    binned = (uint2*)(g + (size_t)N_NODES * 20); // E uint2, 8MB
  uint2*    sorted = binned + N_EDGES;                   // E uint2, 8MB
  unsigned* offs_g = (unsigned*)(sorted + N_EDGES);      // N
  unsigned* ends_g = offs_g + N_NODES;                   // N
  unsigned* bcnt   = ends_g + N_NODES;                   // NB
  unsigned* boffs  = bcnt + NB;                          // NB+1
  unsigned* gcur   = boffs + NB + 1;                     // NB

  hipMemsetAsync(bcnt, 0, NB * sizeof(unsigned), stream);
  hist_buckets<<<N_EDGES / 4096, 256, 0, stream>>>(ei, bcnt);
  scan_buckets<<<1, 256, 0, stream>>>(bcnt, boffs, gcur);
  bin_pass<<<BLK_A, 256, 0, stream>>>(ei, ew, gcur, binned);
  bucket_sort<<<NB, 256, 0, stream>>>(boffs, binned, sorted, offs_g, ends_g);

  gemm1<<<N_NODES / 64, 256, 0, stream>>>(x, W1, h1);
  agg1_gemm2<<<N_NODES / 16, 256, 0, stream>>>(offs_g, ends_g, sorted, h1, b1, W2, g);
  aggregate2<<<N_NODES / 16, 320, 0, stream>>>(offs_g, ends_g, sorted, g, b2, out);
}

// Round 4
// 287.632 us; speedup vs baseline: 4.1745x; 1.1137x over previous
//
#include <hip/hip_runtime.h>

#define N_NODES 65536
#define N_EDGES 1048576
#define NB 256            // coarse buckets = dst >> 8
#define EPB_A 2048        // edges per block in bin_pass
#define BLK_A (N_EDGES / EPB_A)   // 512
#define EPT_A (EPB_A / 256)       // 8 edges per thread

typedef __attribute__((ext_vector_type(8))) short short8v;   // 8 bf16 (4 VGPRs)
typedef __attribute__((ext_vector_type(4))) float float4v;   // MFMA C/D

// fp32 -> bf16 round-to-nearest-even
__device__ __forceinline__ unsigned short f2bf(float f) {
  unsigned u = __float_as_uint(f);
  unsigned r = u + 0x7FFFu + ((u >> 16) & 1u);
  return (unsigned short)(r >> 16);
}

// ---------------------------------------------------------------------------
// JAX threefry2x32, partitionable path: bits[i] = x0^x1 of
// threefry2x32(key=(0,42), counter=(0,i)); keep = MSB==0.  [verified R1]
// ---------------------------------------------------------------------------
__device__ __forceinline__ bool keep_mask(unsigned idx) {
  const unsigned k0 = 0u, k1 = 42u;
  const unsigned k2 = 0x1BD11BDAu ^ k0 ^ k1;
  unsigned x0 = 0u;
  unsigned x1 = idx;
  x0 += k0; x1 += k1;
#define TF_ROUND(r) { x0 += x1; x1 = (x1 << (r)) | (x1 >> (32 - (r))); x1 ^= x0; }
  TF_ROUND(13) TF_ROUND(15) TF_ROUND(26) TF_ROUND(6)
  x0 += k1; x1 += k2 + 1u;
  TF_ROUND(17) TF_ROUND(29) TF_ROUND(16) TF_ROUND(24)
  x0 += k2; x1 += k0 + 2u;
  TF_ROUND(13) TF_ROUND(15) TF_ROUND(26) TF_ROUND(6)
  x0 += k0; x1 += k1 + 3u;
  TF_ROUND(17) TF_ROUND(29) TF_ROUND(16) TF_ROUND(24)
  x0 += k1; x1 += k2 + 4u;
  TF_ROUND(13) TF_ROUND(15) TF_ROUND(26) TF_ROUND(6)
  x0 += k2; x1 += k0 + 5u;
#undef TF_ROUND
  return ((x0 ^ x1) & 0x80000000u) == 0u;
}

// ===========================================================================
// Sort stage 1: coarse-bucket histogram (LDS-privatized)
// ===========================================================================
__global__ __launch_bounds__(256) void hist_buckets(const int* __restrict__ ei,
                                                    unsigned* __restrict__ bcnt) {
  __shared__ unsigned cnt[NB];
  const int t = threadIdx.x;
  cnt[t] = 0u;
  __syncthreads();
  const int e0 = blockIdx.x * 4096;
#pragma unroll
  for (int j = 0; j < 16; ++j) {
    int d = ei[N_EDGES + e0 + t + j * 256];
    atomicAdd(&cnt[d >> 8], 1u);
  }
  __syncthreads();
  atomicAdd(&bcnt[t], cnt[t]);
}

// ===========================================================================
// Sort stage 2: scan 256 bucket counts -> bucket offsets + grab cursors
// ===========================================================================
__global__ __launch_bounds__(256) void scan_buckets(const unsigned* __restrict__ bcnt,
                                                    unsigned* __restrict__ boffs,
                                                    unsigned* __restrict__ gcur) {
  __shared__ unsigned ls[NB];
  const int t = threadIdx.x;
  unsigned v = bcnt[t];
  ls[t] = v;
  __syncthreads();
  for (int d = 1; d < NB; d <<= 1) {
    unsigned u = (t >= d) ? ls[t - d] : 0u;
    __syncthreads();
    ls[t] += u;
    __syncthreads();
  }
  unsigned excl = ls[t] - v;
  boffs[t] = excl;
  gcur[t] = excl;
  if (t == NB - 1) boffs[NB] = ls[t];
}

// ===========================================================================
// Sort stage 3: multisplit — LDS-stage edges by bucket, write contiguous runs
// pack: x = src | (dst << 16)   (both < 65536), y = weight bits
// ===========================================================================
__global__ __launch_bounds__(256) void bin_pass(const int* __restrict__ ei,
                                                const float* __restrict__ ew,
                                                unsigned* __restrict__ gcur,
                                                uint2* __restrict__ binned) {
  __shared__ unsigned cnt[NB], lofs[NB], lcur[NB], gbase[NB];
  __shared__ uint2 stage[EPB_A];
  const int t = threadIdx.x;
  const int e0 = blockIdx.x * EPB_A;
  cnt[t] = 0u;
  lcur[t] = 0u;
  __syncthreads();
  unsigned pk[EPT_A], pw[EPT_A];
#pragma unroll
  for (int j = 0; j < EPT_A; ++j) {
    int e = e0 + t + j * 256;
    unsigned s = (unsigned)ei[e];
    unsigned d = (unsigned)ei[N_EDGES + e];
    pk[j] = s | (d << 16);
    pw[j] = __float_as_uint(ew[e]);
    atomicAdd(&cnt[d >> 8], 1u);
  }
  __syncthreads();
  lofs[t] = cnt[t];
  __syncthreads();
  for (int d = 1; d < NB; d <<= 1) {
    unsigned u = (t >= d) ? lofs[t - d] : 0u;
    __syncthreads();
    lofs[t] += u;
    __syncthreads();
  }
  unsigned incl = lofs[t];
  lofs[t] = incl - cnt[t];
  gbase[t] = atomicAdd(&gcur[t], cnt[t]);
  __syncthreads();
#pragma unroll
  for (int j = 0; j < EPT_A; ++j) {
    unsigned b = pk[j] >> 24;
    unsigned slot = lofs[b] + atomicAdd(&lcur[b], 1u);
    stage[slot] = make_uint2(pk[j], pw[j]);
  }
  __syncthreads();
  for (int s = t; s < EPB_A; s += 256) {
    uint2 u = stage[s];
    unsigned b = u.x >> 24;
    binned[gbase[b] + ((unsigned)s - lofs[b])] = u;
  }
}

// ===========================================================================
// Sort stage 4: per-bucket counting sort by dst low-8; emits CSR offs/ends.
// ===========================================================================
__global__ __launch_bounds__(256) void bucket_sort(const unsigned* __restrict__ boffs,
                                                   const uint2* __restrict__ binned,
                                                   uint2* __restrict__ sorted,
                                                   unsigned* __restrict__ offs_g,
                                                   unsigned* __restrict__ ends_g) {
  __shared__ unsigned cnt[NB], cur[NB];
  const int t = threadIdx.x;
  const int b = blockIdx.x;
  const unsigned lo = boffs[b], hi = boffs[b + 1];
  cnt[t] = 0u;
  __syncthreads();
  for (unsigned i = lo + t; i < hi; i += 256) {
    unsigned lo8 = (binned[i].x >> 16) & 255u;
    atomicAdd(&cnt[lo8], 1u);
  }
  __syncthreads();
  cur[t] = cnt[t];
  __syncthreads();
  for (int d = 1; d < NB; d <<= 1) {
    unsigned u = (t >= d) ? cur[t - d] : 0u;
    __syncthreads();
    cur[t] += u;
    __syncthreads();
  }
  unsigned excl = cur[t] - cnt[t];
  unsigned node_start = lo + excl;
  offs_g[b * NB + t] = node_start;
  ends_g[b * NB + t] = node_start + cnt[t];
  __syncthreads();
  cur[t] = excl;
  __syncthreads();
  for (unsigned i = lo + t; i < hi; i += 256) {
    uint2 u = binned[i];
    unsigned lo8 = (u.x >> 16) & 255u;
    unsigned p = lo + atomicAdd(&cur[lo8], 1u);
    sorted[p] = make_uint2(u.x & 0xFFFFu, u.y);
  }
}

// ===========================================================================
// prep_w1: Wt[ch][k] = bf16(W1[k][ch]), K zero-padded 300 -> 320
// ===========================================================================
__global__ __launch_bounds__(256) void prep_w1(const float* __restrict__ W1,
                                               unsigned short* __restrict__ Wt) {
  int i = blockIdx.x * 256 + threadIdx.x;
  if (i >= 64 * 320) return;
  int ch = i / 320, k = i % 320;
  float v = (k < 300) ? W1[k * 64 + ch] : 0.0f;
  Wt[i] = f2bf(v);
}

// ===========================================================================
// gemm1_mfma: h1 = x @ W1 via bf16 MFMA 16x16x32.
// Block: 64 nodes x 64 ch, 4 waves; wave w = nodes [w*16, w*16+16) x all 64 ch.
// K padded to 320, K-tile 64. x converted fp32->bf16 inline during staging.
// A frag: A[m=lane&15][k=quad*8+j]; B frag: B[k=quad*8+j][n=lane&15];
// C/D: col=lane&15, row=quad*4+reg.  [layouts verified: learn_hip m89/m120]
// ===========================================================================
__global__ __launch_bounds__(256) void gemm1_mfma(const float* __restrict__ x,
                                                  const unsigned short* __restrict__ Wt,
                                                  float* __restrict__ h1) {
  __shared__ unsigned short As[64][72];  // [node][k], pitch 144B (16B-aligned, +4-bank stagger)
  __shared__ unsigned short Bs[64][72];  // [ch][k]
  const int t = threadIdx.x;
  const int node0 = blockIdx.x * 64;
  const int wave = t >> 6, lane = t & 63;
  const int quad = lane >> 4, l16 = lane & 15;
  float4v acc[4] = {{0.f,0.f,0.f,0.f},{0.f,0.f,0.f,0.f},{0.f,0.f,0.f,0.f},{0.f,0.f,0.f,0.f}};

  for (int kt = 0; kt < 5; ++kt) {
    const int k0 = kt * 64;
    // stage A: 64 nodes x 64 k, fp32 -> bf16 (1024 float4 loads)
    for (int f = t; f < 1024; f += 256) {
      int node = f >> 4;
      int k = (f & 15) * 4;
      uint2 packed;
      if (k0 + k < 300) {   // last tile: k>=44 is zero padding (300-256=44, 11 full float4)
        float4 v = *(const float4*)(x + (size_t)(node0 + node) * 300 + k0 + k);
        packed.x = (unsigned)f2bf(v.x) | ((unsigned)f2bf(v.y) << 16);
        packed.y = (unsigned)f2bf(v.z) | ((unsigned)f2bf(v.w) << 16);
      } else {
        packed.x = 0u; packed.y = 0u;
      }
      *(uint2*)&As[node][k] = packed;
    }
    // stage B: 64 ch x 64 k bf16, 16B copies from Wt
    for (int f = t; f < 512; f += 256) {
      int ch = f >> 3;
      int kq = f & 7;
      uint4 v = *(const uint4*)(Wt + (size_t)ch * 320 + k0 + kq * 8);
      *(uint4*)&Bs[ch][kq * 8] = v;
    }
    __syncthreads();
    short8v a0 = *(const short8v*)&As[wave * 16 + l16][quad * 8];
    short8v a1 = *(const short8v*)&As[wave * 16 + l16][32 + quad * 8];
#pragma unroll
    for (int nt = 0; nt < 4; ++nt) {
      short8v b0 = *(const short8v*)&Bs[nt * 16 + l16][quad * 8];
      short8v b1 = *(const short8v*)&Bs[nt * 16 + l16][32 + quad * 8];
      acc[nt] = __builtin_amdgcn_mfma_f32_16x16x32_bf16(a0, b0, acc[nt], 0, 0, 0);
      acc[nt] = __builtin_amdgcn_mfma_f32_16x16x32_bf16(a1, b1, acc[nt], 0, 0, 0);
    }
    __syncthreads();
  }
  // epilogue: node = node0 + wave*16 + quad*4 + reg; ch = nt*16 + l16
#pragma unroll
  for (int nt = 0; nt < 4; ++nt) {
#pragma unroll
    for (int r = 0; r < 4; ++r) {
      h1[(size_t)(node0 + wave * 16 + quad * 4 + r) * 64 + nt * 16 + l16] = acc[nt][r];
    }
  }
}

// ===========================================================================
// Fused: agg1 = b1 + sum_e w*h1[src]; h2 = mask.relu(agg1)*2; g = h2 @ W2
// ===========================================================================
__global__ __launch_bounds__(256) void agg1_gemm2(const unsigned* __restrict__ offs_g,
                                                  const unsigned* __restrict__ ends_g,
                                                  const uint2* __restrict__ sorted,
                                                  const float* __restrict__ h1,
                                                  const float* __restrict__ b1,
                                                  const float* __restrict__ W2,
                                                  float* __restrict__ g) {
  __shared__ float h2[16][68];
  __shared__ float w2t[20][68];
  const int t = threadIdx.x;
  const int node0 = blockIdx.x * 16;
  for (int i = t; i < 64 * 20; i += 256) {
    w2t[i % 20][i / 20] = W2[i];
  }
  const int n = t >> 4, cg = t & 15;
  const int node = node0 + n;
  const unsigned s = offs_g[node], e_end = ends_g[node];
  float4 acc = *(const float4*)(b1 + cg * 4);
  for (unsigned i = s; i < e_end; ++i) {
    uint2 sw = sorted[i];
    float w = __uint_as_float(sw.y);
    float4 v = *(const float4*)(h1 + (size_t)sw.x * 64 + cg * 4);
    acc.x = fmaf(w, v.x, acc.x);
    acc.y = fmaf(w, v.y, acc.y);
    acc.z = fmaf(w, v.z, acc.z);
    acc.w = fmaf(w, v.w, acc.w);
  }
  const unsigned gi = (unsigned)node * 64u + (unsigned)cg * 4u;
  float r[4] = {acc.x, acc.y, acc.z, acc.w};
#pragma unroll
  for (int j = 0; j < 4; ++j) {
    float v = fmaxf(r[j], 0.0f);
    h2[n][cg * 4 + j] = keep_mask(gi + j) ? v * 2.0f : 0.0f;
  }
  __syncthreads();
  for (int o = t; o < 320; o += 256) {
    int n2 = o / 20, c = o % 20;
    float a = 0.0f;
#pragma unroll
    for (int k = 0; k < 64; k += 4) {
      float4 hv = *(const float4*)(&h2[n2][k]);
      float4 wv = *(const float4*)(&w2t[c][k]);
      a = fmaf(hv.x, wv.x, a);
      a = fmaf(hv.y, wv.y, a);
      a = fmaf(hv.z, wv.z, a);
      a = fmaf(hv.w, wv.w, a);
    }
    g[(size_t)(node0 + n2) * 20 + c] = a;
  }
}

// ===========================================================================
// aggregate2: out[n][c] = b2[c] + sum_{e in CSR(n)} w_e * g[src_e][c]
// ===========================================================================
__global__ __launch_bounds__(320) void aggregate2(const unsigned* __restrict__ offs_g,
                                                  const unsigned* __restrict__ ends_g,
                                                  const uint2* __restrict__ sorted,
                                                  const float* __restrict__ g,
                                                  const float* __restrict__ b2,
                                                  float* __restrict__ out) {
  const int tid = threadIdx.x;
  const int n = blockIdx.x * 16 + tid / 20;
  const int c = tid % 20;
  const unsigned s = offs_g[n], e_end = ends_g[n];
  float acc = b2[c];
  for (unsigned e = s; e < e_end; ++e) {
    uint2 sw = sorted[e];
    acc = fmaf(__uint_as_float(sw.y), g[(size_t)sw.x * 20 + c], acc);
  }
  out[(size_t)n * 20 + c] = acc;
}

extern "C" void kernel_launch(void* const* d_in, const int* in_sizes, int n_in,
                              void* d_out, int out_size, void* d_ws, size_t ws_size,
                              hipStream_t stream) {
  const float* x  = (const float*)d_in[0];
  const int*   ei = (const int*)d_in[1];
  const float* ew = (const float*)d_in[2];
  const float* W1 = (const float*)d_in[3];
  const float* b1 = (const float*)d_in[4];
  const float* W2 = (const float*)d_in[5];
  const float* b2 = (const float*)d_in[6];
  float* out = (float*)d_out;

  // workspace layout (~37.6 MB; ws >= 42 MB confirmed R2)
  float*          h1     = (float*)d_ws;                        // N*64 f, 16MB
  float*          g      = h1 + (size_t)N_NODES * 64;           // N*20 f, 5MB
  uint2*          binned = (uint2*)(g + (size_t)N_NODES * 20);  // E uint2, 8MB
  uint2*          sorted = binned + N_EDGES;                    // E uint2, 8MB
  unsigned*       offs_g = (unsigned*)(sorted + N_EDGES);       // N
  unsigned*       ends_g = offs_g + N_NODES;                    // N
  unsigned short* Wt     = (unsigned short*)(ends_g + N_NODES); // 64*320 bf16, 40KB
  unsigned*       bcnt   = (unsigned*)(Wt + 64 * 320);          // NB
  unsigned*       boffs  = bcnt + NB;                           // NB+1
  unsigned*       gcur   = boffs + NB + 1;                      // NB

  hipMemsetAsync(bcnt, 0, NB * sizeof(unsigned), stream);
  hist_buckets<<<N_EDGES / 4096, 256, 0, stream>>>(ei, bcnt);
  scan_buckets<<<1, 256, 0, stream>>>(bcnt, boffs, gcur);
  bin_pass<<<BLK_A, 256, 0, stream>>>(ei, ew, gcur, binned);
  bucket_sort<<<NB, 256, 0, stream>>>(boffs, binned, sorted, offs_g, ends_g);

  prep_w1<<<(64 * 320 + 255) / 256, 256, 0, stream>>>(W1, Wt);
  gemm1_mfma<<<N_NODES / 64, 256, 0, stream>>>(x, Wt, h1);
  agg1_gemm2<<<N_NODES / 16, 256, 0, stream>>>(offs_g, ends_g, sorted, h1, b1, W2, g);
  aggregate2<<<N_NODES / 16, 320, 0, stream>>>(offs_g, ends_g, sorted, g, b2, out);
}

// Round 5
// 241.598 us; speedup vs baseline: 4.9699x; 1.1905x over previous
//
#include <hip/hip_runtime.h>

#define N_NODES 65536
#define N_EDGES 1048576
#define NB 256            // coarse buckets = dst >> 8
#define EPB_A 2048        // edges per block in bin_pass
#define BLK_A (N_EDGES / EPB_A)   // 512
#define EPT_A (EPB_A / 256)       // 8 edges per thread

typedef __attribute__((ext_vector_type(8))) short short8v;   // 8 bf16 (4 VGPRs)
typedef __attribute__((ext_vector_type(4))) float float4v;   // MFMA C/D

// fp32 -> bf16 round-to-nearest-even
__device__ __forceinline__ unsigned short f2bf(float f) {
  unsigned u = __float_as_uint(f);
  unsigned r = u + 0x7FFFu + ((u >> 16) & 1u);
  return (unsigned short)(r >> 16);
}
__device__ __forceinline__ float bflo(unsigned u) { return __uint_as_float(u << 16); }
__device__ __forceinline__ float bfhi(unsigned u) { return __uint_as_float(u & 0xFFFF0000u); }

// ---------------------------------------------------------------------------
// JAX threefry2x32, partitionable path: bits[i] = x0^x1 of
// threefry2x32(key=(0,42), counter=(0,i)); keep = MSB==0.  [verified R1]
// ---------------------------------------------------------------------------
__device__ __forceinline__ bool keep_mask(unsigned idx) {
  const unsigned k0 = 0u, k1 = 42u;
  const unsigned k2 = 0x1BD11BDAu ^ k0 ^ k1;
  unsigned x0 = 0u;
  unsigned x1 = idx;
  x0 += k0; x1 += k1;
#define TF_ROUND(r) { x0 += x1; x1 = (x1 << (r)) | (x1 >> (32 - (r))); x1 ^= x0; }
  TF_ROUND(13) TF_ROUND(15) TF_ROUND(26) TF_ROUND(6)
  x0 += k1; x1 += k2 + 1u;
  TF_ROUND(17) TF_ROUND(29) TF_ROUND(16) TF_ROUND(24)
  x0 += k2; x1 += k0 + 2u;
  TF_ROUND(13) TF_ROUND(15) TF_ROUND(26) TF_ROUND(6)
  x0 += k0; x1 += k1 + 3u;
  TF_ROUND(17) TF_ROUND(29) TF_ROUND(16) TF_ROUND(24)
  x0 += k1; x1 += k2 + 4u;
  TF_ROUND(13) TF_ROUND(15) TF_ROUND(26) TF_ROUND(6)
  x0 += k2; x1 += k0 + 5u;
#undef TF_ROUND
  return ((x0 ^ x1) & 0x80000000u) == 0u;
}

// ===========================================================================
// Sort stage 1: coarse-bucket histogram (LDS-privatized)
// ===========================================================================
__global__ __launch_bounds__(256) void hist_buckets(const int* __restrict__ ei,
                                                    unsigned* __restrict__ bcnt) {
  __shared__ unsigned cnt[NB];
  const int t = threadIdx.x;
  cnt[t] = 0u;
  __syncthreads();
  const int e0 = blockIdx.x * 4096;
#pragma unroll
  for (int j = 0; j < 16; ++j) {
    int d = ei[N_EDGES + e0 + t + j * 256];
    atomicAdd(&cnt[d >> 8], 1u);
  }
  __syncthreads();
  atomicAdd(&bcnt[t], cnt[t]);
}

// ===========================================================================
// Sort stage 2: scan 256 bucket counts -> bucket offsets + grab cursors
// ===========================================================================
__global__ __launch_bounds__(256) void scan_buckets(const unsigned* __restrict__ bcnt,
                                                    unsigned* __restrict__ boffs,
                                                    unsigned* __restrict__ gcur) {
  __shared__ unsigned ls[NB];
  const int t = threadIdx.x;
  unsigned v = bcnt[t];
  ls[t] = v;
  __syncthreads();
  for (int d = 1; d < NB; d <<= 1) {
    unsigned u = (t >= d) ? ls[t - d] : 0u;
    __syncthreads();
    ls[t] += u;
    __syncthreads();
  }
  unsigned excl = ls[t] - v;
  boffs[t] = excl;
  gcur[t] = excl;
  if (t == NB - 1) boffs[NB] = ls[t];
}

// ===========================================================================
// Sort stage 3: multisplit — LDS-stage edges by bucket, write contiguous runs
// pack: x = src | (dst << 16), y = weight fp32 bits
// ===========================================================================
__global__ __launch_bounds__(256) void bin_pass(const int* __restrict__ ei,
                                                const float* __restrict__ ew,
                                                unsigned* __restrict__ gcur,
                                                uint2* __restrict__ binned) {
  __shared__ unsigned cnt[NB], lofs[NB], lcur[NB], gbase[NB];
  __shared__ uint2 stage[EPB_A];
  const int t = threadIdx.x;
  const int e0 = blockIdx.x * EPB_A;
  cnt[t] = 0u;
  lcur[t] = 0u;
  __syncthreads();
  unsigned pk[EPT_A], pw[EPT_A];
#pragma unroll
  for (int j = 0; j < EPT_A; ++j) {
    int e = e0 + t + j * 256;
    unsigned s = (unsigned)ei[e];
    unsigned d = (unsigned)ei[N_EDGES + e];
    pk[j] = s | (d << 16);
    pw[j] = __float_as_uint(ew[e]);
    atomicAdd(&cnt[d >> 8], 1u);
  }
  __syncthreads();
  lofs[t] = cnt[t];
  __syncthreads();
  for (int d = 1; d < NB; d <<= 1) {
    unsigned u = (t >= d) ? lofs[t - d] : 0u;
    __syncthreads();
    lofs[t] += u;
    __syncthreads();
  }
  unsigned incl = lofs[t];
  lofs[t] = incl - cnt[t];
  gbase[t] = atomicAdd(&gcur[t], cnt[t]);
  __syncthreads();
#pragma unroll
  for (int j = 0; j < EPT_A; ++j) {
    unsigned b = pk[j] >> 24;
    unsigned slot = lofs[b] + atomicAdd(&lcur[b], 1u);
    stage[slot] = make_uint2(pk[j], pw[j]);
  }
  __syncthreads();
  for (int s = t; s < EPB_A; s += 256) {
    uint2 u = stage[s];
    unsigned b = u.x >> 24;
    binned[gbase[b] + ((unsigned)s - lofs[b])] = u;
  }
}

// ===========================================================================
// Sort stage 4: per-bucket counting sort by dst low-8; emits CSR offs/ends.
// sorted entry compressed to 4B: src | bf16(w) << 16
// ===========================================================================
__global__ __launch_bounds__(256) void bucket_sort(const unsigned* __restrict__ boffs,
                                                   const uint2* __restrict__ binned,
                                                   unsigned* __restrict__ sortedc,
                                                   unsigned* __restrict__ offs_g,
                                                   unsigned* __restrict__ ends_g) {
  __shared__ unsigned cnt[NB], cur[NB];
  const int t = threadIdx.x;
  const int b = blockIdx.x;
  const unsigned lo = boffs[b], hi = boffs[b + 1];
  cnt[t] = 0u;
  __syncthreads();
  for (unsigned i = lo + t; i < hi; i += 256) {
    unsigned lo8 = (binned[i].x >> 16) & 255u;
    atomicAdd(&cnt[lo8], 1u);
  }
  __syncthreads();
  cur[t] = cnt[t];
  __syncthreads();
  for (int d = 1; d < NB; d <<= 1) {
    unsigned u = (t >= d) ? cur[t - d] : 0u;
    __syncthreads();
    cur[t] += u;
    __syncthreads();
  }
  unsigned excl = cur[t] - cnt[t];
  unsigned node_start = lo + excl;
  offs_g[b * NB + t] = node_start;
  ends_g[b * NB + t] = node_start + cnt[t];
  __syncthreads();
  cur[t] = excl;
  __syncthreads();
  for (unsigned i = lo + t; i < hi; i += 256) {
    uint2 u = binned[i];
    unsigned lo8 = (u.x >> 16) & 255u;
    unsigned p = lo + atomicAdd(&cur[lo8], 1u);
    sortedc[p] = (u.x & 0xFFFFu) | ((unsigned)f2bf(__uint_as_float(u.y)) << 16);
  }
}

// ===========================================================================
// prep_w1: Wt[ch][k] = bf16(W1[k][ch]), K zero-padded 300 -> 320
// ===========================================================================
__global__ __launch_bounds__(256) void prep_w1(const float* __restrict__ W1,
                                               unsigned short* __restrict__ Wt) {
  int i = blockIdx.x * 256 + threadIdx.x;
  if (i >= 64 * 320) return;
  int ch = i / 320, k = i % 320;
  float v = (k < 300) ? W1[k * 64 + ch] : 0.0f;
  Wt[i] = f2bf(v);
}

// ===========================================================================
// gemm1_mfma: h1 = x @ W1 via bf16 MFMA 16x16x32; h1 stored bf16 (8 MB).
// ===========================================================================
__global__ __launch_bounds__(256) void gemm1_mfma(const float* __restrict__ x,
                                                  const unsigned short* __restrict__ Wt,
                                                  unsigned short* __restrict__ h1b) {
  __shared__ unsigned short As[64][72];
  __shared__ unsigned short Bs[64][72];
  const int t = threadIdx.x;
  const int node0 = blockIdx.x * 64;
  const int wave = t >> 6, lane = t & 63;
  const int quad = lane >> 4, l16 = lane & 15;
  float4v acc[4] = {{0.f,0.f,0.f,0.f},{0.f,0.f,0.f,0.f},{0.f,0.f,0.f,0.f},{0.f,0.f,0.f,0.f}};

  for (int kt = 0; kt < 5; ++kt) {
    const int k0 = kt * 64;
    for (int f = t; f < 1024; f += 256) {
      int node = f >> 4;
      int k = (f & 15) * 4;
      uint2 packed;
      if (k0 + k < 300) {
        float4 v = *(const float4*)(x + (size_t)(node0 + node) * 300 + k0 + k);
        packed.x = (unsigned)f2bf(v.x) | ((unsigned)f2bf(v.y) << 16);
        packed.y = (unsigned)f2bf(v.z) | ((unsigned)f2bf(v.w) << 16);
      } else {
        packed.x = 0u; packed.y = 0u;
      }
      *(uint2*)&As[node][k] = packed;
    }
    for (int f = t; f < 512; f += 256) {
      int ch = f >> 3;
      int kq = f & 7;
      uint4 v = *(const uint4*)(Wt + (size_t)ch * 320 + k0 + kq * 8);
      *(uint4*)&Bs[ch][kq * 8] = v;
    }
    __syncthreads();
    short8v a0 = *(const short8v*)&As[wave * 16 + l16][quad * 8];
    short8v a1 = *(const short8v*)&As[wave * 16 + l16][32 + quad * 8];
#pragma unroll
    for (int nt = 0; nt < 4; ++nt) {
      short8v b0 = *(const short8v*)&Bs[nt * 16 + l16][quad * 8];
      short8v b1 = *(const short8v*)&Bs[nt * 16 + l16][32 + quad * 8];
      acc[nt] = __builtin_amdgcn_mfma_f32_16x16x32_bf16(a0, b0, acc[nt], 0, 0, 0);
      acc[nt] = __builtin_amdgcn_mfma_f32_16x16x32_bf16(a1, b1, acc[nt], 0, 0, 0);
    }
    __syncthreads();
  }
#pragma unroll
  for (int nt = 0; nt < 4; ++nt) {
#pragma unroll
    for (int r = 0; r < 4; ++r) {
      h1b[(size_t)(node0 + wave * 16 + quad * 4 + r) * 64 + nt * 16 + l16] = f2bf(acc[nt][r]);
    }
  }
}

// ===========================================================================
// Fused: agg1 = b1 + sum_e w*h1[src]; h2 = mask.relu(agg1)*2; g = h2 @ W2
// h1 bf16 gather (uint2 = 4ch/lane), edge loop unrolled x4 for MLP.
// g stored bf16 padded to 32 ch (one 64B line per node).
// ===========================================================================
__global__ __launch_bounds__(256) void agg1_gemm2(const unsigned* __restrict__ offs_g,
                                                  const unsigned* __restrict__ ends_g,
                                                  const unsigned* __restrict__ sortedc,
                                                  const unsigned short* __restrict__ h1b,
                                                  const float* __restrict__ b1,
                                                  const float* __restrict__ W2,
                                                  unsigned* __restrict__ g32u) {
  __shared__ float h2[16][68];
  __shared__ float w2t[20][68];
  const int t = threadIdx.x;
  const int node0 = blockIdx.x * 16;
  for (int i = t; i < 64 * 20; i += 256) {
    w2t[i % 20][i / 20] = W2[i];
  }
  const int n = t >> 4, cg = t & 15;
  const int node = node0 + n;
  const unsigned s = offs_g[node], e_end = ends_g[node];
  float4 acc = *(const float4*)(b1 + cg * 4);
  unsigned i = s;
  for (; i + 4 <= e_end; i += 4) {
    unsigned e0 = sortedc[i], e1 = sortedc[i + 1], e2 = sortedc[i + 2], e3 = sortedc[i + 3];
    uint2 v0 = *(const uint2*)(h1b + ((size_t)(e0 & 0xFFFFu)) * 64 + cg * 4);
    uint2 v1 = *(const uint2*)(h1b + ((size_t)(e1 & 0xFFFFu)) * 64 + cg * 4);
    uint2 v2 = *(const uint2*)(h1b + ((size_t)(e2 & 0xFFFFu)) * 64 + cg * 4);
    uint2 v3 = *(const uint2*)(h1b + ((size_t)(e3 & 0xFFFFu)) * 64 + cg * 4);
    float w0 = bfhi(e0), w1 = bfhi(e1), w2 = bfhi(e2), w3 = bfhi(e3);
    acc.x = fmaf(w0, bflo(v0.x), acc.x); acc.y = fmaf(w0, bfhi(v0.x), acc.y);
    acc.z = fmaf(w0, bflo(v0.y), acc.z); acc.w = fmaf(w0, bfhi(v0.y), acc.w);
    acc.x = fmaf(w1, bflo(v1.x), acc.x); acc.y = fmaf(w1, bfhi(v1.x), acc.y);
    acc.z = fmaf(w1, bflo(v1.y), acc.z); acc.w = fmaf(w1, bfhi(v1.y), acc.w);
    acc.x = fmaf(w2, bflo(v2.x), acc.x); acc.y = fmaf(w2, bfhi(v2.x), acc.y);
    acc.z = fmaf(w2, bflo(v2.y), acc.z); acc.w = fmaf(w2, bfhi(v2.y), acc.w);
    acc.x = fmaf(w3, bflo(v3.x), acc.x); acc.y = fmaf(w3, bfhi(v3.x), acc.y);
    acc.z = fmaf(w3, bflo(v3.y), acc.z); acc.w = fmaf(w3, bfhi(v3.y), acc.w);
  }
  for (; i < e_end; ++i) {
    unsigned e0 = sortedc[i];
    uint2 v0 = *(const uint2*)(h1b + ((size_t)(e0 & 0xFFFFu)) * 64 + cg * 4);
    float w0 = bfhi(e0);
    acc.x = fmaf(w0, bflo(v0.x), acc.x); acc.y = fmaf(w0, bfhi(v0.x), acc.y);
    acc.z = fmaf(w0, bflo(v0.y), acc.z); acc.w = fmaf(w0, bfhi(v0.y), acc.w);
  }
  const unsigned gi = (unsigned)node * 64u + (unsigned)cg * 4u;
  float r[4] = {acc.x, acc.y, acc.z, acc.w};
#pragma unroll
  for (int j = 0; j < 4; ++j) {
    float v = fmaxf(r[j], 0.0f);
    h2[n][cg * 4 + j] = keep_mask(gi + j) ? v * 2.0f : 0.0f;
  }
  __syncthreads();
  // gemm2 tail: lane cg computes ch {2cg, 2cg+1}; pads (cg>=10) written as 0
  float d0 = 0.0f, d1 = 0.0f;
  if (cg < 10) {
    const int c0 = cg * 2, c1 = cg * 2 + 1;
#pragma unroll
    for (int k = 0; k < 64; k += 4) {
      float4 hv = *(const float4*)(&h2[n][k]);
      float4 w0 = *(const float4*)(&w2t[c0][k]);
      float4 w1 = *(const float4*)(&w2t[c1][k]);
      d0 = fmaf(hv.x, w0.x, d0); d0 = fmaf(hv.y, w0.y, d0);
      d0 = fmaf(hv.z, w0.z, d0); d0 = fmaf(hv.w, w0.w, d0);
      d1 = fmaf(hv.x, w1.x, d1); d1 = fmaf(hv.y, w1.y, d1);
      d1 = fmaf(hv.z, w1.z, d1); d1 = fmaf(hv.w, w1.w, d1);
    }
  }
  unsigned packed = (cg < 10) ? ((unsigned)f2bf(d0) | ((unsigned)f2bf(d1) << 16)) : 0u;
  g32u[(size_t)node * 16 + cg] = packed;
}

// ===========================================================================
// aggregate2: out[n][c] = b2[c] + sum_e w * g[src][c]
// g bf16 padded 32ch; 16 lanes/node, uint gather (2ch), unroll x4.
// ===========================================================================
__global__ __launch_bounds__(256) void aggregate2(const unsigned* __restrict__ offs_g,
                                                  const unsigned* __restrict__ ends_g,
                                                  const unsigned* __restrict__ sortedc,
                                                  const unsigned* __restrict__ g32u,
                                                  const float* __restrict__ b2,
                                                  float* __restrict__ out) {
  const int t = threadIdx.x;
  const int n = blockIdx.x * 16 + (t >> 4);
  const int cg = t & 15;
  const unsigned s = offs_g[n], e_end = ends_g[n];
  float ax = 0.0f, ay = 0.0f;
  unsigned i = s;
  for (; i + 4 <= e_end; i += 4) {
    unsigned e0 = sortedc[i], e1 = sortedc[i + 1], e2 = sortedc[i + 2], e3 = sortedc[i + 3];
    unsigned v0 = g32u[(size_t)(e0 & 0xFFFFu) * 16 + cg];
    unsigned v1 = g32u[(size_t)(e1 & 0xFFFFu) * 16 + cg];
    unsigned v2 = g32u[(size_t)(e2 & 0xFFFFu) * 16 + cg];
    unsigned v3 = g32u[(size_t)(e3 & 0xFFFFu) * 16 + cg];
    float w0 = bfhi(e0), w1 = bfhi(e1), w2 = bfhi(e2), w3 = bfhi(e3);
    ax = fmaf(w0, bflo(v0), ax); ay = fmaf(w0, bfhi(v0), ay);
    ax = fmaf(w1, bflo(v1), ax); ay = fmaf(w1, bfhi(v1), ay);
    ax = fmaf(w2, bflo(v2), ax); ay = fmaf(w2, bfhi(v2), ay);
    ax = fmaf(w3, bflo(v3), ax); ay = fmaf(w3, bfhi(v3), ay);
  }
  for (; i < e_end; ++i) {
    unsigned e0 = sortedc[i];
    unsigned v0 = g32u[(size_t)(e0 & 0xFFFFu) * 16 + cg];
    float w0 = bfhi(e0);
    ax = fmaf(w0, bflo(v0), ax); ay = fmaf(w0, bfhi(v0), ay);
  }
  if (cg < 10) {
    float2 o = make_float2(ax + b2[cg * 2], ay + b2[cg * 2 + 1]);
    *(float2*)(out + (size_t)n * 20 + cg * 2) = o;
  }
}

extern "C" void kernel_launch(void* const* d_in, const int* in_sizes, int n_in,
                              void* d_out, int out_size, void* d_ws, size_t ws_size,
                              hipStream_t stream) {
  const float* x  = (const float*)d_in[0];
  const int*   ei = (const int*)d_in[1];
  const float* ew = (const float*)d_in[2];
  const float* W1 = (const float*)d_in[3];
  const float* b1 = (const float*)d_in[4];
  const float* W2 = (const float*)d_in[5];
  const float* b2 = (const float*)d_in[6];
  float* out = (float*)d_out;

  // workspace layout (~24.6 MB; ws >= 42 MB confirmed R2)
  unsigned short* h1b    = (unsigned short*)d_ws;                 // N*64 bf16, 8MB
  unsigned*       g32u   = (unsigned*)(h1b + (size_t)N_NODES * 64);   // N*16 uint (32ch bf16), 4MB
  uint2*          binned = (uint2*)(g32u + (size_t)N_NODES * 16); // E uint2, 8MB
  unsigned*       sortedc = (unsigned*)(binned + N_EDGES);        // E uint, 4MB
  unsigned*       offs_g = sortedc + N_EDGES;                     // N
  unsigned*       ends_g = offs_g + N_NODES;                      // N
  unsigned short* Wt     = (unsigned short*)(ends_g + N_NODES);   // 64*320 bf16, 40KB
  unsigned*       bcnt   = (unsigned*)(Wt + 64 * 320);            // NB
  unsigned*       boffs  = bcnt + NB;                             // NB+1
  unsigned*       gcur   = boffs + NB + 1;                        // NB

  hipMemsetAsync(bcnt, 0, NB * sizeof(unsigned), stream);
  hist_buckets<<<N_EDGES / 4096, 256, 0, stream>>>(ei, bcnt);
  scan_buckets<<<1, 256, 0, stream>>>(bcnt, boffs, gcur);
  bin_pass<<<BLK_A, 256, 0, stream>>>(ei, ew, gcur, binned);
  bucket_sort<<<NB, 256, 0, stream>>>(boffs, binned, sortedc, offs_g, ends_g);

  prep_w1<<<(64 * 320 + 255) / 256, 256, 0, stream>>>(W1, Wt);
  gemm1_mfma<<<N_NODES / 64, 256, 0, stream>>>(x, Wt, h1b);
  agg1_gemm2<<<N_NODES / 16, 256, 0, stream>>>(offs_g, ends_g, sortedc, h1b, b1, W2, g32u);
  aggregate2<<<N_NODES / 16, 256, 0, stream>>>(offs_g, ends_g, sortedc, g32u, b2, out);
}